// Round 13
// baseline (563.416 us; speedup 1.0000x reference)
//
#include <hip/hip_runtime.h>
#include <hip/hip_cooperative_groups.h>
#include <math.h>

// Bit-matches a dtype-faithful numpy float32 mirror of the jax reference
// (proven r8): no FMA, numpy pairwise_sum tap order, sequential f32 cumsums,
// first-occurrence argmax. DECISION-PATH FP ORDER IS FROZEN.
// r13: r11 mono-kernel with the P2 chunk-coverage bug fixed (512 -> 2048
// float4s per chunk; r12 histogrammed only 25% of each image).
#pragma clang fp contract(off)

namespace cg = cooperative_groups;

struct GaussW { float w[9]; };

__global__ __launch_bounds__(256, 4) void mono_kernel(const float* __restrict__ x,
                                                      float* __restrict__ blurred,
                                                      float* __restrict__ pmin,
                                                      float* __restrict__ pmax,
                                                      unsigned* __restrict__ hist,
                                                      unsigned* __restrict__ cnt,
                                                      float* __restrict__ t,
                                                      float* __restrict__ out,
                                                      GaussW gw, int nimg) {
    #pragma clang fp contract(off)
    __shared__ union {
        struct { float s_in[72][72]; float s_vb[64][72]; } b;   // 39168 B
        struct { unsigned sh[2048]; } h;                        // 8192 B
        struct { float counts[256], centers[256], w1[256], w2[256], cs[256], rcs[256]; } o;
    } u;
    __shared__ float s_lo, s_hi;
    __shared__ float smin[4], smax[4];
    __shared__ int s_last;

    const int tid = threadIdx.x;
    const int wv = tid >> 6, ln = tid & 63;
    cg::grid_group grid = cg::this_grid();

    // ---- P0: zero hist + counters (ws is poisoned 0xAA every call) ----
    if (blockIdx.x < (unsigned)nimg) {
        hist[blockIdx.x * 256 + tid] = 0u;
        if (tid == 0) cnt[blockIdx.x] = 0u;
    }

    // ---- P1: blur tiles (64x64 out, 72x72 halo), numpy pairwise tap order ----
    const int ntiles = nimg * 64;
    for (int tile = blockIdx.x; tile < ntiles; tile += gridDim.x) {
        const int b = tile >> 6, ty = (tile >> 3) & 7, tx = tile & 7;
        const int r0 = ty * 64, c0 = tx * 64;
        const float* img0 = x + (size_t)b * 4 * 262144;
        __syncthreads();
        for (int i = tid; i < 72 * 72; i += 256) {
            int r = i / 72, c = i - r * 72;
            int gr = min(max(r0 + r - 4, 0), 511);
            int gc = min(max(c0 + c - 4, 0), 511);
            float v = img0[gr * 512 + gc];
            u.b.s_in[r][c] = fminf(fmaxf(v * 0.5f + 0.5f, 0.0f), 1.0f);
        }
        __syncthreads();
        for (int i = tid; i < 1152; i += 256) {
            int sr = (i / 72) * 4, c = i % 72;
            float t0 = u.b.s_in[sr + 0][c], t1 = u.b.s_in[sr + 1][c], t2 = u.b.s_in[sr + 2][c];
            float t3 = u.b.s_in[sr + 3][c], t4 = u.b.s_in[sr + 4][c], t5 = u.b.s_in[sr + 5][c];
            float t6 = u.b.s_in[sr + 6][c], t7 = u.b.s_in[sr + 7][c], t8 = u.b.s_in[sr + 8][c];
            float t9 = u.b.s_in[sr + 9][c], t10 = u.b.s_in[sr + 10][c], t11 = u.b.s_in[sr + 11][c];
            {
                float q0 = t0 * gw.w[0], q1 = t1 * gw.w[1], q2 = t2 * gw.w[2], q3 = t3 * gw.w[3];
                float q4 = t4 * gw.w[4], q5 = t5 * gw.w[5], q6 = t6 * gw.w[6], q7 = t7 * gw.w[7];
                float acc = ((q0 + q1) + (q2 + q3)) + ((q4 + q5) + (q6 + q7));
                u.b.s_vb[sr + 0][c] = acc + t8 * gw.w[8];
            }
            {
                float q0 = t1 * gw.w[0], q1 = t2 * gw.w[1], q2 = t3 * gw.w[2], q3 = t4 * gw.w[3];
                float q4 = t5 * gw.w[4], q5 = t6 * gw.w[5], q6 = t7 * gw.w[6], q7 = t8 * gw.w[7];
                float acc = ((q0 + q1) + (q2 + q3)) + ((q4 + q5) + (q6 + q7));
                u.b.s_vb[sr + 1][c] = acc + t9 * gw.w[8];
            }
            {
                float q0 = t2 * gw.w[0], q1 = t3 * gw.w[1], q2 = t4 * gw.w[2], q3 = t5 * gw.w[3];
                float q4 = t6 * gw.w[4], q5 = t7 * gw.w[5], q6 = t8 * gw.w[6], q7 = t9 * gw.w[7];
                float acc = ((q0 + q1) + (q2 + q3)) + ((q4 + q5) + (q6 + q7));
                u.b.s_vb[sr + 2][c] = acc + t10 * gw.w[8];
            }
            {
                float q0 = t3 * gw.w[0], q1 = t4 * gw.w[1], q2 = t5 * gw.w[2], q3 = t6 * gw.w[3];
                float q4 = t7 * gw.w[4], q5 = t8 * gw.w[5], q6 = t9 * gw.w[6], q7 = t10 * gw.w[7];
                float acc = ((q0 + q1) + (q2 + q3)) + ((q4 + q5) + (q6 + q7));
                u.b.s_vb[sr + 3][c] = acc + t11 * gw.w[8];
            }
        }
        __syncthreads();
        float lmin = 1e30f, lmax = -1e30f;
        float* bimg = blurred + (size_t)b * 262144;
        for (int i = tid; i < 1024; i += 256) {
            int r = i >> 4, cc = (i & 15) * 4;
            float4 va = *(const float4*)&u.b.s_vb[r][cc];
            float4 vb = *(const float4*)&u.b.s_vb[r][cc + 4];
            float4 vc = *(const float4*)&u.b.s_vb[r][cc + 8];
            float t0 = va.x, t1 = va.y, t2 = va.z, t3 = va.w;
            float t4 = vb.x, t5 = vb.y, t6 = vb.z, t7 = vb.w;
            float t8 = vc.x, t9 = vc.y, t10 = vc.z, t11 = vc.w;
            float4 o;
            {
                float q0 = t0 * gw.w[0], q1 = t1 * gw.w[1], q2 = t2 * gw.w[2], q3 = t3 * gw.w[3];
                float q4 = t4 * gw.w[4], q5 = t5 * gw.w[5], q6 = t6 * gw.w[6], q7 = t7 * gw.w[7];
                float acc = ((q0 + q1) + (q2 + q3)) + ((q4 + q5) + (q6 + q7));
                o.x = acc + t8 * gw.w[8];
            }
            {
                float q0 = t1 * gw.w[0], q1 = t2 * gw.w[1], q2 = t3 * gw.w[2], q3 = t4 * gw.w[3];
                float q4 = t5 * gw.w[4], q5 = t6 * gw.w[5], q6 = t7 * gw.w[6], q7 = t8 * gw.w[7];
                float acc = ((q0 + q1) + (q2 + q3)) + ((q4 + q5) + (q6 + q7));
                o.y = acc + t9 * gw.w[8];
            }
            {
                float q0 = t2 * gw.w[0], q1 = t3 * gw.w[1], q2 = t4 * gw.w[2], q3 = t5 * gw.w[3];
                float q4 = t6 * gw.w[4], q5 = t7 * gw.w[5], q6 = t8 * gw.w[6], q7 = t9 * gw.w[7];
                float acc = ((q0 + q1) + (q2 + q3)) + ((q4 + q5) + (q6 + q7));
                o.z = acc + t10 * gw.w[8];
            }
            {
                float q0 = t3 * gw.w[0], q1 = t4 * gw.w[1], q2 = t5 * gw.w[2], q3 = t6 * gw.w[3];
                float q4 = t7 * gw.w[4], q5 = t8 * gw.w[5], q6 = t9 * gw.w[6], q7 = t10 * gw.w[7];
                float acc = ((q0 + q1) + (q2 + q3)) + ((q4 + q5) + (q6 + q7));
                o.w = acc + t11 * gw.w[8];
            }
            *(float4*)&bimg[(size_t)(r0 + r) * 512 + (c0 + cc)] = o;
            lmin = fminf(fminf(fminf(lmin, o.x), fminf(o.y, o.z)), o.w);
            lmax = fmaxf(fmaxf(fmaxf(lmax, o.x), fmaxf(o.y, o.z)), o.w);
        }
        for (int off = 32; off >= 1; off >>= 1) {
            lmin = fminf(lmin, __shfl_down(lmin, off));
            lmax = fmaxf(lmax, __shfl_down(lmax, off));
        }
        if (ln == 0) { smin[wv] = lmin; smax[wv] = lmax; }
        __syncthreads();
        if (tid == 0) {
            float mn = fminf(fminf(smin[0], smin[1]), fminf(smin[2], smin[3]));
            float mx = fmaxf(fmaxf(smax[0], smax[1]), fmaxf(smax[2], smax[3]));
            int bid = ty * 8 + tx;
            pmin[b * 64 + bid] = mn;
            pmax[b * 64 + bid] = mx;
        }
    }

    grid.sync();

    // ---- P2: histogram (8-copy LDS) + otsu by last-finishing block per image ----
    // Each image = 65536 float4s, split into 32 chunks of 2048 float4s.
    const int nunits = nimg * 32;
    for (int unit = blockIdx.x; unit < nunits; unit += gridDim.x) {
        const int b = unit >> 5, chunk = unit & 31;
        __syncthreads();
        for (int i = tid; i < 2048; i += 256) u.h.sh[i] = 0u;
        if (wv == 0) {
            float v = pmin[b * 64 + ln];
            for (int off = 32; off >= 1; off >>= 1) v = fminf(v, __shfl_down(v, off));
            if (ln == 0) s_lo = v;
        } else if (wv == 1) {
            float v = pmax[b * 64 + ln];
            for (int off = 32; off >= 1; off >>= 1) v = fmaxf(v, __shfl_down(v, off));
            if (ln == 0) s_hi = v;
        }
        __syncthreads();
        const float lo = s_lo, hi = s_hi;
        const float width = (hi - lo) * 0.00390625f;      // /256 exact (pow2)
        const float denom = fmaxf(width, 1e-12f);
        const int copy = tid & 7;
        const float4* img = (const float4*)(blurred + (size_t)b * 262144);
        for (int i = chunk * 2048 + tid; i < (chunk + 1) * 2048; i += 256) {
            float4 v = img[i];
            int i0 = min(max((int)floorf((v.x - lo) / denom), 0), 255);
            int i1 = min(max((int)floorf((v.y - lo) / denom), 0), 255);
            int i2 = min(max((int)floorf((v.z - lo) / denom), 0), 255);
            int i3 = min(max((int)floorf((v.w - lo) / denom), 0), 255);
            atomicAdd(&u.h.sh[i0 * 8 + copy], 1u);
            atomicAdd(&u.h.sh[i1 * 8 + copy], 1u);
            atomicAdd(&u.h.sh[i2 * 8 + copy], 1u);
            atomicAdd(&u.h.sh[i3 * 8 + copy], 1u);
        }
        __syncthreads();
        unsigned c8 = 0;
        {
            int base = tid * 8;
#pragma unroll
            for (int k = 0; k < 8; ++k) c8 += u.h.sh[base + k];
        }
        if (c8) atomicAdd(&hist[b * 256 + tid], c8);
        __threadfence();          // release our hist adds before the counter bump
        __syncthreads();
        if (tid == 0) {
            unsigned v = atomicAdd(&cnt[b], 1u);
            s_last = (v == 31u);
        }
        __syncthreads();
        if (s_last) {
            __threadfence();      // acquire: all 32 chunks' hist adds visible
            u.o.counts[tid] = (float)hist[b * 256 + tid];
            u.o.centers[tid] = lo + ((float)tid + 0.5f) * width;
            __syncthreads();
            if (ln == 0) {
                if (wv == 0) {            // w1: ascending cumsum of counts
                    float a = 0.f;
                    for (int i0 = 0; i0 < 256; i0 += 8) {
                        float c0 = u.o.counts[i0+0], c1 = u.o.counts[i0+1], c2 = u.o.counts[i0+2], c3 = u.o.counts[i0+3];
                        float c4 = u.o.counts[i0+4], c5 = u.o.counts[i0+5], c6 = u.o.counts[i0+6], c7 = u.o.counts[i0+7];
                        a = a + c0; u.o.w1[i0+0] = a; a = a + c1; u.o.w1[i0+1] = a;
                        a = a + c2; u.o.w1[i0+2] = a; a = a + c3; u.o.w1[i0+3] = a;
                        a = a + c4; u.o.w1[i0+4] = a; a = a + c5; u.o.w1[i0+5] = a;
                        a = a + c6; u.o.w1[i0+6] = a; a = a + c7; u.o.w1[i0+7] = a;
                    }
                } else if (wv == 1) {     // w2: descending cumsum of counts
                    float a = 0.f;
                    for (int i0 = 255; i0 >= 7; i0 -= 8) {
                        float c0 = u.o.counts[i0-0], c1 = u.o.counts[i0-1], c2 = u.o.counts[i0-2], c3 = u.o.counts[i0-3];
                        float c4 = u.o.counts[i0-4], c5 = u.o.counts[i0-5], c6 = u.o.counts[i0-6], c7 = u.o.counts[i0-7];
                        a = a + c0; u.o.w2[i0-0] = a; a = a + c1; u.o.w2[i0-1] = a;
                        a = a + c2; u.o.w2[i0-2] = a; a = a + c3; u.o.w2[i0-3] = a;
                        a = a + c4; u.o.w2[i0-4] = a; a = a + c5; u.o.w2[i0-5] = a;
                        a = a + c6; u.o.w2[i0-6] = a; a = a + c7; u.o.w2[i0-7] = a;
                    }
                } else if (wv == 2) {     // cs: ascending cumsum of counts*centers
                    float a = 0.f;
                    for (int i0 = 0; i0 < 256; i0 += 8) {
                        float q0 = u.o.counts[i0+0] * u.o.centers[i0+0], q1 = u.o.counts[i0+1] * u.o.centers[i0+1];
                        float q2 = u.o.counts[i0+2] * u.o.centers[i0+2], q3 = u.o.counts[i0+3] * u.o.centers[i0+3];
                        float q4 = u.o.counts[i0+4] * u.o.centers[i0+4], q5 = u.o.counts[i0+5] * u.o.centers[i0+5];
                        float q6 = u.o.counts[i0+6] * u.o.centers[i0+6], q7 = u.o.counts[i0+7] * u.o.centers[i0+7];
                        a = a + q0; u.o.cs[i0+0] = a; a = a + q1; u.o.cs[i0+1] = a;
                        a = a + q2; u.o.cs[i0+2] = a; a = a + q3; u.o.cs[i0+3] = a;
                        a = a + q4; u.o.cs[i0+4] = a; a = a + q5; u.o.cs[i0+5] = a;
                        a = a + q6; u.o.cs[i0+6] = a; a = a + q7; u.o.cs[i0+7] = a;
                    }
                } else {                  // rcs: descending cumsum of counts*centers
                    float a = 0.f;
                    for (int i0 = 255; i0 >= 7; i0 -= 8) {
                        float q0 = u.o.counts[i0-0] * u.o.centers[i0-0], q1 = u.o.counts[i0-1] * u.o.centers[i0-1];
                        float q2 = u.o.counts[i0-2] * u.o.centers[i0-2], q3 = u.o.counts[i0-3] * u.o.centers[i0-3];
                        float q4 = u.o.counts[i0-4] * u.o.centers[i0-4], q5 = u.o.counts[i0-5] * u.o.centers[i0-5];
                        float q6 = u.o.counts[i0-6] * u.o.centers[i0-6], q7 = u.o.counts[i0-7] * u.o.centers[i0-7];
                        a = a + q0; u.o.rcs[i0-0] = a; a = a + q1; u.o.rcs[i0-1] = a;
                        a = a + q2; u.o.rcs[i0-2] = a; a = a + q3; u.o.rcs[i0-3] = a;
                        a = a + q4; u.o.rcs[i0-4] = a; a = a + q5; u.o.rcs[i0-5] = a;
                        a = a + q6; u.o.rcs[i0-6] = a; a = a + q7; u.o.rcs[i0-7] = a;
                    }
                }
            }
            __syncthreads();
            if (wv == 0) {
                float best = -1e30f; int bi = 0x7fffffff;
#pragma unroll
                for (int k = 0; k < 4; ++k) {
                    int i = ln + 64 * k;
                    if (i < 255) {
                        float m1 = u.o.cs[i] / fmaxf(u.o.w1[i], 1e-12f);
                        float m2 = u.o.rcs[i + 1] / fmaxf(u.o.w2[i + 1], 1e-12f);
                        float d = m1 - m2;
                        float v = (u.o.w1[i] * u.o.w2[i + 1]) * (d * d);
                        if (v > best) { best = v; bi = i; }
                    }
                }
                for (int off = 32; off >= 1; off >>= 1) {
                    float ov = __shfl_down(best, off);
                    int   oi = __shfl_down(bi, off);
                    if (ov > best || (ov == best && oi < bi)) { best = ov; bi = oi; }
                }
                if (ln == 0) t[b] = u.o.centers[bi];
            }
        }
    }

    grid.sync();

    // ---- P3: final blend ----
    const int total4 = nimg * 65536;
    for (int i = blockIdx.x * 256 + tid; i < total4; i += gridDim.x * 256) {
        int b = i >> 16;
        int p = i & 65535;
        float tb = t[b];
        float4 bl = ((const float4*)(blurred + (size_t)b * 262144))[p];
        float4 m;
        m.x = (bl.x > tb) ? 1.0f : bl.x;
        m.y = (bl.y > tb) ? 1.0f : bl.y;
        m.z = (bl.z > tb) ? 1.0f : bl.z;
        m.w = (bl.w > tb) ? 1.0f : bl.w;
        const float4* xim = (const float4*)(x + (size_t)b * 4 * 262144);
        float4* oim = (float4*)(out + (size_t)b * 3 * 262144);
#pragma unroll
        for (int c = 0; c < 3; ++c) {
            float4 rgb = xim[(size_t)(c + 1) * 65536 + p];
            float4 o;
            o.x = fminf(fmaxf(m.x * rgb.x + (1.0f - m.x), 0.f), 1.f);
            o.y = fminf(fmaxf(m.y * rgb.y + (1.0f - m.y), 0.f), 1.f);
            o.z = fminf(fmaxf(m.z * rgb.z + (1.0f - m.z), 0.f), 1.f);
            o.w = fminf(fmaxf(m.w * rgb.w + (1.0f - m.w), 0.f), 1.f);
            oim[(size_t)c * 65536 + p] = o;
        }
    }
}

extern "C" void kernel_launch(void* const* d_in, const int* in_sizes, int n_in,
                              void* d_out, int out_size, void* d_ws, size_t ws_size,
                              hipStream_t stream) {
    const float* x = (const float*)d_in[0];
    float* out = (float*)d_out;
    int nimg = in_sizes[0] / (4 * 262144);   // 32 images of 4x512x512

    float* blurred = (float*)d_ws;                                   // nimg*262144 f32
    unsigned* hist = (unsigned*)(blurred + (size_t)nimg * 262144);   // nimg*256 u32
    unsigned* cnt = hist + (size_t)nimg * 256;                       // nimg u32
    float* pmin = (float*)(cnt + nimg);                              // nimg*64
    float* pmax = pmin + (size_t)nimg * 64;                          // nimg*64
    float* t = pmax + (size_t)nimg * 64;                             // nimg

    // Weights, numpy-f32-mirror (frozen): CR-f32 exp at exact inputs,
    // np.sum pairwise order for n=9, w = k/s in f32.
    GaussW gw;
    float kk[9];
    for (int i = 0; i < 9; ++i) {
        double d = (double)(i - 4);
        kk[i] = (float)exp(-0.5 * d * d);
    }
    float s = ((kk[0] + kk[1]) + (kk[2] + kk[3])) + ((kk[4] + kk[5]) + (kk[6] + kk[7]));
    s = s + kk[8];
    for (int i = 0; i < 9; ++i) gw.w[i] = kk[i] / s;

    void* args[] = { (void*)&x, (void*)&blurred, (void*)&pmin, (void*)&pmax,
                     (void*)&hist, (void*)&cnt, (void*)&t, (void*)&out,
                     (void*)&gw, (void*)&nimg };
    hipLaunchCooperativeKernel((void*)mono_kernel, dim3(1024), dim3(256), args, 0, stream);
}